// Round 7
// baseline (139.617 us; speedup 1.0000x reference)
//
#include <hip/hip_runtime.h>
#include <stdint.h>

typedef __bf16 bf16x8 __attribute__((ext_vector_type(8)));
typedef float  f32x4  __attribute__((ext_vector_type(4)));
typedef unsigned short u16;

#define AS1 __attribute__((address_space(1)))
#define AS3 __attribute__((address_space(3)))
#define G2L(gp, lp) __builtin_amdgcn_global_load_lds( \
    (const AS1 unsigned int*)(uintptr_t)(gp), \
    (AS3 unsigned int*)(uintptr_t)(lp), 16, 0, 0)

static __device__ __forceinline__ u16 f32_to_bf16(float f) {
    unsigned u = __float_as_uint(f);
    u += 0x7fffu + ((u >> 16) & 1u);
    return (u16)(u >> 16);
}

// unambiguous bf16 pair pack: lo -> bits[15:0], hi -> bits[31:16]
static __device__ __forceinline__ unsigned pack_bf16(float lo, float hi) {
    return (unsigned)f32_to_bf16(lo) | ((unsigned)f32_to_bf16(hi) << 16);
}

static __device__ __forceinline__ float fast_exp2(float x) {
    return __builtin_amdgcn_exp2f(x);
}

static __device__ __forceinline__ f32x4 mfma16(bf16x8 a, bf16x8 b, f32x4 c) {
    return __builtin_amdgcn_mfma_f32_16x16x32_bf16(a, b, c, 0, 0, 0);
}

// ---------------- fused fp32 -> bf16 convert for x, W_qkv, W_out ----------------
__global__ void cvt3_k(const float* __restrict__ a, const float* __restrict__ b,
                       const float* __restrict__ c, u16* __restrict__ out) {
    const int i = blockIdx.x * blockDim.x + threadIdx.x;   // vec4 index
    const float* src; int off;
    if (i < 1572864)      { src = a; off = 0; }
    else if (i < 2015232) { src = b; off = 1572864; }
    else                  { src = c; off = 2015232; }
    const float4 v = reinterpret_cast<const float4*>(src)[i - off];
    reinterpret_cast<uint2*>(out)[i] = make_uint2(pack_bf16(v.x, v.y), pack_bf16(v.z, v.w));
}

// ---------------- bf16 GEMM: C[M,N] = A[M,K] @ B[N,K]^T + bias ----------------
// 128x128 tile, BK=64, 2-phase prefetch: stage t+1 issued before compute t,
// vmcnt(0)+barrier at iteration top. Double-buffered LDS, XCD-swizzled grid.
template<int OUTF32>
__global__ __launch_bounds__(256, 2) void gemm_bt_k(const u16* __restrict__ A, const u16* __restrict__ B,
                                                    const float* __restrict__ bias, void* __restrict__ Cp,
                                                    int M, int N, int K, int nbx) {
    __shared__ __align__(16) u16 As[2][128 * 64];
    __shared__ __align__(16) u16 Bs[2][128 * 64];
    const int id = blockIdx.x;
    const int cpx = gridDim.x >> 3;                       // grid divisible by 8
    const int swz = (id & 7) * cpx + (id >> 3);           // bijective XCD swizzle
    const int bx = swz % nbx, by = swz / nbx;
    const int t = threadIdx.x, w = t >> 6, l = t & 63, lr = l & 15, lg = l >> 4;
    const int wr = w >> 1, wc = w & 1;
    const long rowBase = (long)by * 128;
    const long colBase = (long)bx * 128;

    const f32x4 z = {0.f, 0.f, 0.f, 0.f};
    f32x4 acc[4][4];
    #pragma unroll
    for (int m = 0; m < 4; ++m)
        #pragma unroll
        for (int n = 0; n < 4; ++n) acc[m][n] = z;

    const int kSteps = K >> 6;
    // prologue: stage tile 0 into buf 0
    #pragma unroll
    for (int i = 0; i < 4; ++i) {
        const int c = i * 256 + t, row = c >> 3, ch = c & 7;
        const int sch = ch ^ (row & 7);
        G2L(A + (rowBase + row) * K + sch * 8, &As[0][(i * 256 + w * 64) * 8]);
        G2L(B + (colBase + row) * K + sch * 8, &Bs[0][(i * 256 + w * 64) * 8]);
    }
    for (int kt = 0; kt < kSteps; ++kt) {
        const int cur = kt & 1;
        asm volatile("s_waitcnt vmcnt(0)" ::: "memory");   // my stage writes landed
        __builtin_amdgcn_sched_barrier(0);
        __builtin_amdgcn_s_barrier();                      // everyone's landed; prev reads done
        __builtin_amdgcn_sched_barrier(0);
        if (kt + 1 < kSteps) {                             // issue next-tile stage (hidden under compute)
            const int k0 = (kt + 1) << 6;
            #pragma unroll
            for (int i = 0; i < 4; ++i) {
                const int c = i * 256 + t, row = c >> 3, ch = c & 7;
                const int sch = ch ^ (row & 7);
                G2L(A + (rowBase + row) * K + k0 + sch * 8, &As[cur ^ 1][(i * 256 + w * 64) * 8]);
                G2L(B + (colBase + row) * K + k0 + sch * 8, &Bs[cur ^ 1][(i * 256 + w * 64) * 8]);
            }
        }
        __builtin_amdgcn_sched_barrier(0);
        #pragma unroll
        for (int kk = 0; kk < 2; ++kk) {
            bf16x8 af[4], bfr[4];
            #pragma unroll
            for (int m = 0; m < 4; ++m) {
                const int row = wr * 64 + m * 16 + lr;
                af[m] = *reinterpret_cast<const bf16x8*>(&As[cur][row * 64 + (((kk * 4 + lg) ^ (lr & 7)) << 3)]);
            }
            #pragma unroll
            for (int n = 0; n < 4; ++n) {
                const int row = wc * 64 + n * 16 + lr;
                bfr[n] = *reinterpret_cast<const bf16x8*>(&Bs[cur][row * 64 + (((kk * 4 + lg) ^ (lr & 7)) << 3)]);
            }
            #pragma unroll
            for (int m = 0; m < 4; ++m)
                #pragma unroll
                for (int n = 0; n < 4; ++n) acc[m][n] = mfma16(af[m], bfr[n], acc[m][n]);
        }
    }
    #pragma unroll
    for (int n = 0; n < 4; ++n) {
        const long gc = colBase + wc * 64 + n * 16 + lr;
        const float bv = bias[gc];
        #pragma unroll
        for (int m = 0; m < 4; ++m) {
            const long gr = rowBase + wr * 64 + m * 16 + lg * 4;
            #pragma unroll
            for (int r = 0; r < 4; ++r) {
                const float v = acc[m][n][r] + bv;
                if (OUTF32) reinterpret_cast<float*>(Cp)[(gr + r) * N + gc] = v;
                else        reinterpret_cast<u16*>(Cp)[(gr + r) * N + gc] = f32_to_bf16(v);
            }
        }
    }
}

// ---------------- V transpose with PV k-permutation pi' ----------------
// vt[bh][d][pos p] = V[key = (p>>5)*32 + ((p>>2)&1)*16 + ((p>>3)&3)*4 + (p&3)][d]
__global__ __launch_bounds__(256) void transpose_v_k(const u16* __restrict__ qkv, u16* __restrict__ vt) {
    const int bh = blockIdx.y, b = bh / 12, h = bh % 12;
    const int nt = blockIdx.x;
    __shared__ __align__(16) u16 Ts[64][72];   // [key][d]
    const int t = threadIdx.x;
    const int rr = t >> 2;
    #pragma unroll
    for (int i = 0; i < 2; ++i) {
        const int ch = (t & 3) + i * 4;
        const u16* src = qkv + (long)(b * 1024 + nt * 64 + rr) * 2304 + 1536 + h * 64 + ch * 8;
        *reinterpret_cast<uint4*>(&Ts[rr][ch * 8]) = *reinterpret_cast<const uint4*>(src);
    }
    __syncthreads();
    #pragma unroll
    for (int i = 0; i < 2; ++i) {
        const int ch = (t & 3) + i * 4;   // ch in 0..7, pos p = ch*8+j
        u16 vals[8];
        #pragma unroll
        for (int j = 0; j < 8; ++j)
            vals[j] = Ts[(ch >> 2) * 32 + (j >> 2) * 16 + (ch & 3) * 4 + (j & 3)][rr];
        u16* dst = vt + (long)(bh * 64 + rr) * 1024 + nt * 64 + ch * 8;
        *reinterpret_cast<uint4*>(dst) = *reinterpret_cast<const uint4*>(vals);
    }
}

// ---------------- flash attention v6: all-register, tile-split waves ----------------
// Each of 4 waves owns k-tiles {w, w+4, w+8, w+12} and computes S^T = K@Q^T for
// all 64 q via swapped-operand MFMA: lane holds P[q=lr] for its 16 keys, and the
// 8 PV k-positions per kk are lane-local under pi' (baked into vt). K/V/Q are
// loaded global->regs (no LDS staging, no loop barriers). Partial O reduced via
// LDS at the end (stride-68 pad => 2-way conflicts = free).
__global__ __launch_bounds__(256, 1) void attn_k(const u16* __restrict__ qkv, const u16* __restrict__ vt,
                                                 u16* __restrict__ outp) {
    const int id = blockIdx.x;
    const int bh = id % 96, qt = id / 96;   // same-bh blocks -> same XCD (96%8==0)
    const int b = bh / 12, h = bh % 12;
    const int t = threadIdx.x, w = t >> 6, l = t & 63, lr = l & 15, lg = l >> 4;
    __shared__ __align__(16) float red[4 * 64 * 68 + 4 * 64];   // 70.7 KB

    // Q fragments for all 64 q-rows (B-operand: lane provides Q[q=lr][d-chunk lg])
    const u16* qb = qkv + (long)(b * 1024 + qt * 64) * 2304 + h * 64;
    bf16x8 aq[4][2];
    #pragma unroll
    for (int qf = 0; qf < 4; ++qf)
        #pragma unroll
        for (int kk = 0; kk < 2; ++kk)
            aq[qf][kk] = *reinterpret_cast<const bf16x8*>(qb + (long)(qf * 16 + lr) * 2304 + (kk * 4 + lg) * 8);

    const u16* kb = qkv + (long)(b * 1024) * 2304 + 768 + h * 64;
    const u16* vb = vt + (long)bh * 64 * 1024;

    const f32x4 z = {0.f, 0.f, 0.f, 0.f};
    f32x4 o[4][4];   // [qf][n]: O[q=qf*16+lg*4+r][d=n*16+lr], partial over my keys
    #pragma unroll
    for (int qf = 0; qf < 4; ++qf)
        #pragma unroll
        for (int n = 0; n < 4; ++n) o[qf][n] = z;
    float lacc[4] = {0.f, 0.f, 0.f, 0.f};   // [qf]: partial denom for q=qf*16+lr
    const float sc2 = 0.052058773f;          // 768^-0.5 * log2(e)

    #pragma unroll
    for (int ti = 0; ti < 4; ++ti) {
        const int kt = ti * 4 + w;   // my wave's exclusive k-tile
        bf16x8 bk[4][2], vv[2][4];
        #pragma unroll
        for (int kc = 0; kc < 4; ++kc)
            #pragma unroll
            for (int kk = 0; kk < 2; ++kk)
                bk[kc][kk] = *reinterpret_cast<const bf16x8*>(
                    kb + (long)(kt * 64 + kc * 16 + lr) * 2304 + (kk * 4 + lg) * 8);
        #pragma unroll
        for (int kk = 0; kk < 2; ++kk)
            #pragma unroll
            for (int n = 0; n < 4; ++n)
                vv[kk][n] = *reinterpret_cast<const bf16x8*>(
                    vb + (long)(n * 16 + lr) * 1024 + kt * 64 + (kk * 4 + lg) * 8);
        // S^T = K @ Q^T: s[kc][qf] => S[key=kc*16+lg*4+r][q=qf*16+lr]
        f32x4 s[4][4];
        #pragma unroll
        for (int kc = 0; kc < 4; ++kc)
            #pragma unroll
            for (int qf = 0; qf < 4; ++qf) s[kc][qf] = z;
        #pragma unroll
        for (int kk = 0; kk < 2; ++kk)
            #pragma unroll
            for (int kc = 0; kc < 4; ++kc)
                #pragma unroll
                for (int qf = 0; qf < 4; ++qf)
                    s[kc][qf] = mfma16(bk[kc][kk], aq[qf][kk], s[kc][qf]);
        // softmax-lite + in-register P pack (pos j=c*4+r of pa[qf][kk] = pv[2kk+c][r])
        bf16x8 pa[4][2];
        #pragma unroll
        for (int qf = 0; qf < 4; ++qf) {
            float pv[4][4];
            #pragma unroll
            for (int kc = 0; kc < 4; ++kc)
                #pragma unroll
                for (int r = 0; r < 4; ++r) {
                    pv[kc][r] = fast_exp2(s[kc][qf][r] * sc2);
                    lacc[qf] += pv[kc][r];
                }
            uint4 u0, u1;
            u0.x = pack_bf16(pv[0][0], pv[0][1]); u0.y = pack_bf16(pv[0][2], pv[0][3]);
            u0.z = pack_bf16(pv[1][0], pv[1][1]); u0.w = pack_bf16(pv[1][2], pv[1][3]);
            u1.x = pack_bf16(pv[2][0], pv[2][1]); u1.y = pack_bf16(pv[2][2], pv[2][3]);
            u1.z = pack_bf16(pv[3][0], pv[3][1]); u1.w = pack_bf16(pv[3][2], pv[3][3]);
            pa[qf][0] = *reinterpret_cast<bf16x8*>(&u0);
            pa[qf][1] = *reinterpret_cast<bf16x8*>(&u1);
        }
        // O += P @ V (pi'-consistent on both operands)
        #pragma unroll
        for (int kk = 0; kk < 2; ++kk)
            #pragma unroll
            for (int n = 0; n < 4; ++n)
                #pragma unroll
                for (int qf = 0; qf < 4; ++qf)
                    o[qf][n] = mfma16(pa[qf][kk], vv[kk][n], o[qf][n]);
    }
    // wave-internal denom reduce (lanes lr,+16,+32,+48 hold partials of q=qf*16+lr)
    #pragma unroll
    for (int qf = 0; qf < 4; ++qf) {
        lacc[qf] += __shfl_xor(lacc[qf], 16, 64);
        lacc[qf] += __shfl_xor(lacc[qf], 32, 64);
    }
    // cross-wave reduce via LDS
    float* ored = red;
    float* dnm = red + 4 * 64 * 68;
    #pragma unroll
    for (int qf = 0; qf < 4; ++qf)
        #pragma unroll
        for (int n = 0; n < 4; ++n)
            #pragma unroll
            for (int r = 0; r < 4; ++r)
                ored[(w * 64 + qf * 16 + lg * 4 + r) * 68 + n * 16 + lr] = o[qf][n][r];
    if (l < 16) {
        #pragma unroll
        for (int qf = 0; qf < 4; ++qf) dnm[w * 64 + qf * 16 + lr] = lacc[qf];
    }
    __syncthreads();
    #pragma unroll
    for (int r = 0; r < 4; ++r) {
        const int q = w * 16 + lg * 4 + r;
        const float dq = dnm[q] + dnm[64 + q] + dnm[128 + q] + dnm[192 + q];
        const float inv = 1.0f / dq;
        #pragma unroll
        for (int n = 0; n < 4; ++n) {
            const int d = n * 16 + lr;
            const float sum = ored[q * 68 + d] + ored[(64 + q) * 68 + d]
                            + ored[(128 + q) * 68 + d] + ored[(192 + q) * 68 + d];
            outp[(long)(b * 1024 + qt * 64 + q) * 768 + h * 64 + d] = f32_to_bf16(sum * inv);
        }
    }
}

extern "C" void kernel_launch(void* const* d_in, const int* in_sizes, int n_in,
                              void* d_out, int out_size, void* d_ws, size_t ws_size,
                              hipStream_t stream) {
    (void)in_sizes; (void)n_in; (void)out_size; (void)ws_size;
    const float* x    = (const float*)d_in[0];
    const float* Wqkv = (const float*)d_in[1];
    const float* bqkv = (const float*)d_in[2];
    const float* Wout = (const float*)d_in[3];
    const float* bout = (const float*)d_in[4];

    u16* xb   = (u16*)d_ws;          // 8192*768
    u16* Wqb  = xb  + 6291456;       // 2304*768
    u16* Wob  = Wqb + 1769472;       // 768*768
    u16* qkv  = Wob + 589824;        // 8192*2304
    u16* vtb  = qkv + 18874368;      // 96*64*1024
    u16* attn = vtb + 6291456;       // 8192*768

    cvt3_k<<<8448, 256, 0, stream>>>(x, Wqkv, Wout, xb);

    gemm_bt_k<0><<<1152, 256, 0, stream>>>(xb, Wqb, bqkv, qkv, 8192, 2304, 768, 18);
    transpose_v_k<<<dim3(16, 96), 256, 0, stream>>>(qkv, vtb);
    attn_k<<<1536, 256, 0, stream>>>(qkv, vtb, attn);
    gemm_bt_k<1><<<384, 256, 0, stream>>>(attn, Wob, bout, d_out, 8192, 768, 768, 6);
}

// Round 8
// 116.101 us; speedup vs baseline: 1.2026x; 1.2026x over previous
//
#include <hip/hip_runtime.h>
#include <stdint.h>

typedef __bf16 bf16x8 __attribute__((ext_vector_type(8)));
typedef float  f32x4  __attribute__((ext_vector_type(4)));
typedef unsigned short u16;

#define AS1 __attribute__((address_space(1)))
#define AS3 __attribute__((address_space(3)))
#define G2L(gp, lp) __builtin_amdgcn_global_load_lds( \
    (const AS1 unsigned int*)(uintptr_t)(gp), \
    (AS3 unsigned int*)(uintptr_t)(lp), 16, 0, 0)

static __device__ __forceinline__ u16 f32_to_bf16(float f) {
    unsigned u = __float_as_uint(f);
    u += 0x7fffu + ((u >> 16) & 1u);
    return (u16)(u >> 16);
}

// unambiguous bf16 pair pack: lo -> bits[15:0], hi -> bits[31:16]
static __device__ __forceinline__ unsigned pack_bf16(float lo, float hi) {
    return (unsigned)f32_to_bf16(lo) | ((unsigned)f32_to_bf16(hi) << 16);
}

static __device__ __forceinline__ float fast_exp2(float x) {
    return __builtin_amdgcn_exp2f(x);
}

static __device__ __forceinline__ f32x4 mfma16(bf16x8 a, bf16x8 b, f32x4 c) {
    return __builtin_amdgcn_mfma_f32_16x16x32_bf16(a, b, c, 0, 0, 0);
}

// ---------------- fused fp32 -> bf16 convert for x, W_qkv, W_out ----------------
__global__ void cvt3_k(const float* __restrict__ a, const float* __restrict__ b,
                       const float* __restrict__ c, u16* __restrict__ out) {
    const int i = blockIdx.x * blockDim.x + threadIdx.x;   // vec4 index
    const float* src; int off;
    if (i < 1572864)      { src = a; off = 0; }
    else if (i < 2015232) { src = b; off = 1572864; }
    else                  { src = c; off = 2015232; }
    const float4 v = reinterpret_cast<const float4*>(src)[i - off];
    reinterpret_cast<uint2*>(out)[i] = make_uint2(pack_bf16(v.x, v.y), pack_bf16(v.z, v.w));
}

// ---------------- bf16 GEMM: C[M,N] = A[M,K] @ B[N,K]^T + bias ----------------
// 128x128 tile, BK=64, 2-phase prefetch: stage t+1 issued before compute t,
// vmcnt(0)+barrier at iteration top. Double-buffered LDS, XCD-swizzled grid.
template<int OUTF32>
__global__ __launch_bounds__(256, 2) void gemm_bt_k(const u16* __restrict__ A, const u16* __restrict__ B,
                                                    const float* __restrict__ bias, void* __restrict__ Cp,
                                                    int M, int N, int K, int nbx) {
    __shared__ __align__(16) u16 As[2][128 * 64];
    __shared__ __align__(16) u16 Bs[2][128 * 64];
    const int id = blockIdx.x;
    const int cpx = gridDim.x >> 3;                       // grid divisible by 8
    const int swz = (id & 7) * cpx + (id >> 3);           // bijective XCD swizzle
    const int bx = swz % nbx, by = swz / nbx;
    const int t = threadIdx.x, w = t >> 6, l = t & 63, lr = l & 15, lg = l >> 4;
    const int wr = w >> 1, wc = w & 1;
    const long rowBase = (long)by * 128;
    const long colBase = (long)bx * 128;

    const f32x4 z = {0.f, 0.f, 0.f, 0.f};
    f32x4 acc[4][4];
    #pragma unroll
    for (int m = 0; m < 4; ++m)
        #pragma unroll
        for (int n = 0; n < 4; ++n) acc[m][n] = z;

    const int kSteps = K >> 6;
    // prologue: stage tile 0 into buf 0
    #pragma unroll
    for (int i = 0; i < 4; ++i) {
        const int c = i * 256 + t, row = c >> 3, ch = c & 7;
        const int sch = ch ^ (row & 7);
        G2L(A + (rowBase + row) * K + sch * 8, &As[0][(i * 256 + w * 64) * 8]);
        G2L(B + (colBase + row) * K + sch * 8, &Bs[0][(i * 256 + w * 64) * 8]);
    }
    for (int kt = 0; kt < kSteps; ++kt) {
        const int cur = kt & 1;
        asm volatile("s_waitcnt vmcnt(0)" ::: "memory");   // my stage writes landed
        __builtin_amdgcn_sched_barrier(0);
        __builtin_amdgcn_s_barrier();                      // everyone's landed; prev reads done
        __builtin_amdgcn_sched_barrier(0);
        if (kt + 1 < kSteps) {                             // issue next-tile stage (hidden under compute)
            const int k0 = (kt + 1) << 6;
            #pragma unroll
            for (int i = 0; i < 4; ++i) {
                const int c = i * 256 + t, row = c >> 3, ch = c & 7;
                const int sch = ch ^ (row & 7);
                G2L(A + (rowBase + row) * K + k0 + sch * 8, &As[cur ^ 1][(i * 256 + w * 64) * 8]);
                G2L(B + (colBase + row) * K + k0 + sch * 8, &Bs[cur ^ 1][(i * 256 + w * 64) * 8]);
            }
        }
        __builtin_amdgcn_sched_barrier(0);
        #pragma unroll
        for (int kk = 0; kk < 2; ++kk) {
            bf16x8 af[4], bfr[4];
            #pragma unroll
            for (int m = 0; m < 4; ++m) {
                const int row = wr * 64 + m * 16 + lr;
                af[m] = *reinterpret_cast<const bf16x8*>(&As[cur][row * 64 + (((kk * 4 + lg) ^ (lr & 7)) << 3)]);
            }
            #pragma unroll
            for (int n = 0; n < 4; ++n) {
                const int row = wc * 64 + n * 16 + lr;
                bfr[n] = *reinterpret_cast<const bf16x8*>(&Bs[cur][row * 64 + (((kk * 4 + lg) ^ (lr & 7)) << 3)]);
            }
            #pragma unroll
            for (int m = 0; m < 4; ++m)
                #pragma unroll
                for (int n = 0; n < 4; ++n) acc[m][n] = mfma16(af[m], bfr[n], acc[m][n]);
        }
    }
    #pragma unroll
    for (int n = 0; n < 4; ++n) {
        const long gc = colBase + wc * 64 + n * 16 + lr;
        const float bv = bias[gc];
        #pragma unroll
        for (int m = 0; m < 4; ++m) {
            const long gr = rowBase + wr * 64 + m * 16 + lg * 4;
            #pragma unroll
            for (int r = 0; r < 4; ++r) {
                const float v = acc[m][n][r] + bv;
                if (OUTF32) reinterpret_cast<float*>(Cp)[(gr + r) * N + gc] = v;
                else        reinterpret_cast<u16*>(Cp)[(gr + r) * N + gc] = f32_to_bf16(v);
            }
        }
    }
}

// ---------------- V transpose with PV k-permutation ----------------
// vt[bh][d][tile pos p] = V[key = (p&3)*16 + (p>>2)][d]
__global__ __launch_bounds__(256) void transpose_v_k(const u16* __restrict__ qkv, u16* __restrict__ vt) {
    const int bh = blockIdx.y, b = bh / 12, h = bh % 12;
    const int nt = blockIdx.x;
    __shared__ __align__(16) u16 Ts[64][72];   // [key][d]
    const int t = threadIdx.x;
    const int rr = t >> 2;
    #pragma unroll
    for (int i = 0; i < 2; ++i) {
        const int ch = (t & 3) + i * 4;
        const u16* src = qkv + (long)(b * 1024 + nt * 64 + rr) * 2304 + 1536 + h * 64 + ch * 8;
        *reinterpret_cast<uint4*>(&Ts[rr][ch * 8]) = *reinterpret_cast<const uint4*>(src);
    }
    __syncthreads();
    #pragma unroll
    for (int i = 0; i < 2; ++i) {
        const int ch = (t & 3) + i * 4;
        u16 vals[8];
        #pragma unroll
        for (int j = 0; j < 8; ++j)
            vals[j] = Ts[(j & 3) * 16 + ch * 2 + (j >> 2)][rr];   // key = pi(ch*8+j)
        u16* dst = vt + (long)(bh * 64 + rr) * 1024 + nt * 64 + ch * 8;
        *reinterpret_cast<uint4*>(dst) = *reinterpret_cast<const uint4*>(vals);
    }
}

// ---------------- flash attention v5 (R6-proven) + occupancy 4 ----------------
// Permuted-P softmax (C-packed b64 writes), Q aliased onto Ps (40KB LDS),
// G2L double-buffered K/V, XCD-swizzled 1D grid.
__global__ __launch_bounds__(256, 4) void attn_k(const u16* __restrict__ qkv, const u16* __restrict__ vt,
                                                 u16* __restrict__ outp) {
    const int id = blockIdx.x;
    const int bh = id % 96, qt = id / 96;   // same-bh blocks -> same XCD (96%8==0)
    const int b = bh / 12, h = bh % 12;
    const int t = threadIdx.x, w = t >> 6, l = t & 63, lr = l & 15, lg = l >> 4;
    __shared__ __align__(16) u16 Ks[2][64 * 64];
    __shared__ __align__(16) u16 Vts[2][64 * 64];   // [d][perm key]
    __shared__ __align__(16) u16 Ps[4 * 16 * 64];   // per-wave P; doubles as Q staging

    const u16* kb = qkv + 768 + h * 64;
    const u16* vb = vt + (long)bh * 64 * 1024;

    #pragma unroll
    for (int i = 0; i < 2; ++i) {
        const int c = (i * 4 + w) * 64 + l;
        const int row = c >> 3, sch = (c & 7) ^ (row & 7);
        G2L(kb + (long)(b * 1024 + row) * 2304 + sch * 8, &Ks[0][(i * 4 + w) * 512]);
        G2L(vb + (long)row * 1024 + sch * 8, &Vts[0][(i * 4 + w) * 512]);
    }
    #pragma unroll
    for (int j = 0; j < 2; ++j) {
        const int c = j * 256 + t, row = c >> 3, ch = c & 7;
        const uint4 q = *reinterpret_cast<const uint4*>(
            qkv + (long)(b * 1024 + qt * 64 + row) * 2304 + h * 64 + ch * 8);
        *reinterpret_cast<uint4*>(&Ps[row * 64 + ((ch ^ (row & 7)) << 3)]) = q;
    }
    __syncthreads();
    bf16x8 aq[2];
    #pragma unroll
    for (int kk = 0; kk < 2; ++kk)
        aq[kk] = *reinterpret_cast<const bf16x8*>(&Ps[(w * 16 + lr) * 64 + (((kk * 4 + lg) ^ (lr & 7)) << 3)]);

    const f32x4 z = {0.f, 0.f, 0.f, 0.f};
    f32x4 o[4] = {z, z, z, z};
    float lacc[4] = {0.f, 0.f, 0.f, 0.f};
    const float sc2 = 0.052058773f;   // 768^-0.5 * log2(e)

    for (int kt = 0; kt < 16; ++kt) {
        const int cur = kt & 1;
        asm volatile("s_waitcnt vmcnt(0)" ::: "memory");
        __builtin_amdgcn_sched_barrier(0);
        __builtin_amdgcn_s_barrier();
        __builtin_amdgcn_sched_barrier(0);
        if (kt < 15) {
            const int ktn = kt + 1;
            #pragma unroll
            for (int i = 0; i < 2; ++i) {
                const int c = (i * 4 + w) * 64 + l;
                const int row = c >> 3, sch = (c & 7) ^ (row & 7);
                G2L(kb + (long)(b * 1024 + ktn * 64 + row) * 2304 + sch * 8, &Ks[cur ^ 1][(i * 4 + w) * 512]);
                G2L(vb + (long)row * 1024 + ktn * 64 + sch * 8, &Vts[cur ^ 1][(i * 4 + w) * 512]);
            }
        }
        __builtin_amdgcn_sched_barrier(0);
        // S = Q @ K^T   (s[kc][r] = S[q=lg*4+r][key=kc*16+lr])
        f32x4 s[4] = {z, z, z, z};
        #pragma unroll
        for (int kk = 0; kk < 2; ++kk) {
            #pragma unroll
            for (int kc = 0; kc < 4; ++kc) {
                const int row = kc * 16 + lr;
                bf16x8 bk = *reinterpret_cast<const bf16x8*>(&Ks[cur][row * 64 + (((kk * 4 + lg) ^ (lr & 7)) << 3)]);
                s[kc] = mfma16(aq[kk], bk, s[kc]);
            }
        }
        // softmax-lite, permuted-P pack: row q keys {kc*16+lr} at pos lr*4+kc
        #pragma unroll
        for (int r = 0; r < 4; ++r) {
            const float p0 = fast_exp2(s[0][r] * sc2);
            const float p1 = fast_exp2(s[1][r] * sc2);
            const float p2 = fast_exp2(s[2][r] * sc2);
            const float p3 = fast_exp2(s[3][r] * sc2);
            lacc[r] += (p0 + p1) + (p2 + p3);
            const unsigned w0 = pack_bf16(p0, p1);
            const unsigned w1 = pack_bf16(p2, p3);
            const int q = lg * 4 + r;
            const int csw = (lr >> 1) ^ (q & 7);
            *reinterpret_cast<uint2*>(&Ps[w * 1024 + q * 64 + csw * 8 + (lr & 1) * 4]) = make_uint2(w0, w1);
        }
        // O += P @ V (both sides share permutation pi: pos p -> key (p&3)*16+(p>>2))
        #pragma unroll
        for (int kk = 0; kk < 2; ++kk) {
            bf16x8 pa = *reinterpret_cast<const bf16x8*>(&Ps[w * 1024 + lr * 64 + (((kk * 4 + lg) ^ (lr & 7)) << 3)]);
            #pragma unroll
            for (int n = 0; n < 4; ++n) {
                const int row = n * 16 + lr;
                bf16x8 vbf = *reinterpret_cast<const bf16x8*>(&Vts[cur][row * 64 + (((kk * 4 + lg) ^ (lr & 7)) << 3)]);
                o[n] = mfma16(pa, vbf, o[n]);
            }
        }
    }
    #pragma unroll
    for (int r = 0; r < 4; ++r) {
        float rs = lacc[r];
        #pragma unroll
        for (int off = 1; off < 16; off <<= 1) rs += __shfl_xor(rs, off, 64);
        lacc[r] = rs;
    }
    const int qrow = qt * 64 + w * 16 + lg * 4;
    #pragma unroll
    for (int n = 0; n < 4; ++n) {
        #pragma unroll
        for (int r = 0; r < 4; ++r) {
            const float v = o[n][r] / lacc[r];
            outp[(long)(b * 1024 + qrow + r) * 768 + h * 64 + n * 16 + lr] = f32_to_bf16(v);
        }
    }
}

extern "C" void kernel_launch(void* const* d_in, const int* in_sizes, int n_in,
                              void* d_out, int out_size, void* d_ws, size_t ws_size,
                              hipStream_t stream) {
    (void)in_sizes; (void)n_in; (void)out_size; (void)ws_size;
    const float* x    = (const float*)d_in[0];
    const float* Wqkv = (const float*)d_in[1];
    const float* bqkv = (const float*)d_in[2];
    const float* Wout = (const float*)d_in[3];
    const float* bout = (const float*)d_in[4];

    u16* xb   = (u16*)d_ws;          // 8192*768
    u16* Wqb  = xb  + 6291456;       // 2304*768
    u16* Wob  = Wqb + 1769472;       // 768*768
    u16* qkv  = Wob + 589824;        // 8192*2304
    u16* vtb  = qkv + 18874368;      // 96*64*1024
    u16* attn = vtb + 6291456;       // 8192*768

    cvt3_k<<<8448, 256, 0, stream>>>(x, Wqkv, Wout, xb);

    gemm_bt_k<0><<<1152, 256, 0, stream>>>(xb, Wqb, bqkv, qkv, 8192, 2304, 768, 18);
    transpose_v_k<<<dim3(16, 96), 256, 0, stream>>>(qkv, vtb);
    attn_k<<<1536, 256, 0, stream>>>(qkv, vtb, attn);
    gemm_bt_k<1><<<384, 256, 0, stream>>>(attn, Wob, bout, d_out, 8192, 768, 768, 6);
}

// Round 9
// 114.448 us; speedup vs baseline: 1.2199x; 1.0144x over previous
//
#include <hip/hip_runtime.h>
#include <stdint.h>

typedef __bf16 bf16x8 __attribute__((ext_vector_type(8)));
typedef float  f32x4  __attribute__((ext_vector_type(4)));
typedef unsigned short u16;

#define AS1 __attribute__((address_space(1)))
#define AS3 __attribute__((address_space(3)))
#define G2L(gp, lp) __builtin_amdgcn_global_load_lds( \
    (const AS1 unsigned int*)(uintptr_t)(gp), \
    (AS3 unsigned int*)(uintptr_t)(lp), 16, 0, 0)

static __device__ __forceinline__ u16 f32_to_bf16(float f) {
    unsigned u = __float_as_uint(f);
    u += 0x7fffu + ((u >> 16) & 1u);
    return (u16)(u >> 16);
}

// bf16 pair pack: lo -> bits[15:0], hi -> bits[31:16]
static __device__ __forceinline__ unsigned pack_bf16(float lo, float hi) {
    return (unsigned)f32_to_bf16(lo) | ((unsigned)f32_to_bf16(hi) << 16);
}

static __device__ __forceinline__ float fast_exp2(float x) {
    return __builtin_amdgcn_exp2f(x);
}

static __device__ __forceinline__ f32x4 mfma16(bf16x8 a, bf16x8 b, f32x4 c) {
    return __builtin_amdgcn_mfma_f32_16x16x32_bf16(a, b, c, 0, 0, 0);
}

// ---------------- fused fp32 -> bf16 convert for x, W_qkv, W_out ----------------
__global__ void cvt3_k(const float* __restrict__ a, const float* __restrict__ b,
                       const float* __restrict__ c, u16* __restrict__ out) {
    const int i = blockIdx.x * blockDim.x + threadIdx.x;   // vec4 index
    const float* src; int off;
    if (i < 1572864)      { src = a; off = 0; }
    else if (i < 2015232) { src = b; off = 1572864; }
    else                  { src = c; off = 2015232; }
    const float4 v = reinterpret_cast<const float4*>(src)[i - off];
    reinterpret_cast<uint2*>(out)[i] = make_uint2(pack_bf16(v.x, v.y), pack_bf16(v.z, v.w));
}

// ---------------- bf16 GEMM: C[M,N] = A[M,K] @ B[N,K]^T + bias ----------------
// 128x128 tile, BK=64, 2-phase prefetch, double-buffered LDS, XCD-swizzled grid.
template<int OUTF32>
__global__ __launch_bounds__(256, 2) void gemm_bt_k(const u16* __restrict__ A, const u16* __restrict__ B,
                                                    const float* __restrict__ bias, void* __restrict__ Cp,
                                                    int M, int N, int K, int nbx) {
    __shared__ __align__(16) u16 As[2][128 * 64];
    __shared__ __align__(16) u16 Bs[2][128 * 64];
    const int id = blockIdx.x;
    const int cpx = gridDim.x >> 3;
    const int swz = (id & 7) * cpx + (id >> 3);
    const int bx = swz % nbx, by = swz / nbx;
    const int t = threadIdx.x, w = t >> 6, l = t & 63, lr = l & 15, lg = l >> 4;
    const int wr = w >> 1, wc = w & 1;
    const long rowBase = (long)by * 128;
    const long colBase = (long)bx * 128;

    const f32x4 z = {0.f, 0.f, 0.f, 0.f};
    f32x4 acc[4][4];
    #pragma unroll
    for (int m = 0; m < 4; ++m)
        #pragma unroll
        for (int n = 0; n < 4; ++n) acc[m][n] = z;

    const int kSteps = K >> 6;
    #pragma unroll
    for (int i = 0; i < 4; ++i) {
        const int c = i * 256 + t, row = c >> 3, ch = c & 7;
        const int sch = ch ^ (row & 7);
        G2L(A + (rowBase + row) * K + sch * 8, &As[0][(i * 256 + w * 64) * 8]);
        G2L(B + (colBase + row) * K + sch * 8, &Bs[0][(i * 256 + w * 64) * 8]);
    }
    for (int kt = 0; kt < kSteps; ++kt) {
        const int cur = kt & 1;
        asm volatile("s_waitcnt vmcnt(0)" ::: "memory");
        __builtin_amdgcn_sched_barrier(0);
        __builtin_amdgcn_s_barrier();
        __builtin_amdgcn_sched_barrier(0);
        if (kt + 1 < kSteps) {
            const int k0 = (kt + 1) << 6;
            #pragma unroll
            for (int i = 0; i < 4; ++i) {
                const int c = i * 256 + t, row = c >> 3, ch = c & 7;
                const int sch = ch ^ (row & 7);
                G2L(A + (rowBase + row) * K + k0 + sch * 8, &As[cur ^ 1][(i * 256 + w * 64) * 8]);
                G2L(B + (colBase + row) * K + k0 + sch * 8, &Bs[cur ^ 1][(i * 256 + w * 64) * 8]);
            }
        }
        __builtin_amdgcn_sched_barrier(0);
        #pragma unroll
        for (int kk = 0; kk < 2; ++kk) {
            bf16x8 af[4], bfr[4];
            #pragma unroll
            for (int m = 0; m < 4; ++m) {
                const int row = wr * 64 + m * 16 + lr;
                af[m] = *reinterpret_cast<const bf16x8*>(&As[cur][row * 64 + (((kk * 4 + lg) ^ (lr & 7)) << 3)]);
            }
            #pragma unroll
            for (int n = 0; n < 4; ++n) {
                const int row = wc * 64 + n * 16 + lr;
                bfr[n] = *reinterpret_cast<const bf16x8*>(&Bs[cur][row * 64 + (((kk * 4 + lg) ^ (lr & 7)) << 3)]);
            }
            #pragma unroll
            for (int m = 0; m < 4; ++m)
                #pragma unroll
                for (int n = 0; n < 4; ++n) acc[m][n] = mfma16(af[m], bfr[n], acc[m][n]);
        }
    }
    #pragma unroll
    for (int n = 0; n < 4; ++n) {
        const long gc = colBase + wc * 64 + n * 16 + lr;
        const float bv = bias[gc];
        #pragma unroll
        for (int m = 0; m < 4; ++m) {
            const long gr = rowBase + wr * 64 + m * 16 + lg * 4;
            #pragma unroll
            for (int r = 0; r < 4; ++r) {
                const float v = acc[m][n][r] + bv;
                if (OUTF32) reinterpret_cast<float*>(Cp)[(gr + r) * N + gc] = v;
                else        reinterpret_cast<u16*>(Cp)[(gr + r) * N + gc] = f32_to_bf16(v);
            }
        }
    }
}

// ---------------- V transpose with PV k-permutation ----------------
// vt[bh][d][tile pos p] = V[key = (p&3)*16 + (p>>2)][d]
__global__ __launch_bounds__(256) void transpose_v_k(const u16* __restrict__ qkv, u16* __restrict__ vt) {
    const int bh = blockIdx.y, b = bh / 12, h = bh % 12;
    const int nt = blockIdx.x;
    __shared__ __align__(16) u16 Ts[64][72];   // [key][d]
    const int t = threadIdx.x;
    const int rr = t >> 2;
    #pragma unroll
    for (int i = 0; i < 2; ++i) {
        const int ch = (t & 3) + i * 4;
        const u16* src = qkv + (long)(b * 1024 + nt * 64 + rr) * 2304 + 1536 + h * 64 + ch * 8;
        *reinterpret_cast<uint4*>(&Ts[rr][ch * 8]) = *reinterpret_cast<const uint4*>(src);
    }
    __syncthreads();
    #pragma unroll
    for (int i = 0; i < 2; ++i) {
        const int ch = (t & 3) + i * 4;
        u16 vals[8];
        #pragma unroll
        for (int j = 0; j < 8; ++j)
            vals[j] = Ts[(j & 3) * 16 + ch * 2 + (j >> 2)][rr];   // key = pi(ch*8+j)
        u16* dst = vt + (long)(bh * 64 + rr) * 1024 + nt * 64 + ch * 8;
        *reinterpret_cast<uint4*>(dst) = *reinterpret_cast<const uint4*>(vals);
    }
}

// ---------------- flash attention v6: QBLK=128 ----------------
// 8 q-subtiles per block; each wave owns 2 (qg=0,1). K/V fragments read from
// LDS once and reused across both q-groups; G2L-dbuf staging serves 2x work.
// Permuted-P softmax, Q staged into Ps alias (16KB), XCD-swizzled grid.
__global__ __launch_bounds__(256, 3) void attn_k(const u16* __restrict__ qkv, const u16* __restrict__ vt,
                                                 u16* __restrict__ outp) {
    const int id = blockIdx.x;
    const int bh = id % 96, qt = id / 96;   // qt in 0..7; same-bh -> same XCD
    const int b = bh / 12, h = bh % 12;
    const int t = threadIdx.x, w = t >> 6, l = t & 63, lr = l & 15, lg = l >> 4;
    __shared__ __align__(16) u16 Ks[2][64 * 64];
    __shared__ __align__(16) u16 Vts[2][64 * 64];   // [d][perm key]
    __shared__ __align__(16) u16 Ps[8192];          // 4w x 2qg x 16q x 64; aliases Q staging

    const u16* kb = qkv + 768 + h * 64;
    const u16* vb = vt + (long)bh * 64 * 1024;

    #pragma unroll
    for (int i = 0; i < 2; ++i) {
        const int c = (i * 4 + w) * 64 + l;
        const int row = c >> 3, sch = (c & 7) ^ (row & 7);
        G2L(kb + (long)(b * 1024 + row) * 2304 + sch * 8, &Ks[0][(i * 4 + w) * 512]);
        G2L(vb + (long)row * 1024 + sch * 8, &Vts[0][(i * 4 + w) * 512]);
    }
    // stage 128 Q rows into Ps (swizzled)
    #pragma unroll
    for (int j = 0; j < 4; ++j) {
        const int c = j * 256 + t, row = c >> 3, ch = c & 7;
        const uint4 q = *reinterpret_cast<const uint4*>(
            qkv + (long)(b * 1024 + qt * 128 + row) * 2304 + h * 64 + ch * 8);
        *reinterpret_cast<uint4*>(&Ps[row * 64 + ((ch ^ (row & 7)) << 3)]) = q;
    }
    __syncthreads();
    bf16x8 aq[2][2];
    #pragma unroll
    for (int qg = 0; qg < 2; ++qg)
        #pragma unroll
        for (int kk = 0; kk < 2; ++kk)
            aq[qg][kk] = *reinterpret_cast<const bf16x8*>(
                &Ps[(qg * 64 + w * 16 + lr) * 64 + (((kk * 4 + lg) ^ (lr & 7)) << 3)]);

    const f32x4 z = {0.f, 0.f, 0.f, 0.f};
    f32x4 o[2][4];
    #pragma unroll
    for (int qg = 0; qg < 2; ++qg)
        #pragma unroll
        for (int n = 0; n < 4; ++n) o[qg][n] = z;
    float lacc[2][4] = {{0.f, 0.f, 0.f, 0.f}, {0.f, 0.f, 0.f, 0.f}};
    const float sc2 = 0.052058773f;   // 768^-0.5 * log2(e)

    for (int kt = 0; kt < 16; ++kt) {
        const int cur = kt & 1;
        asm volatile("s_waitcnt vmcnt(0)" ::: "memory");
        __builtin_amdgcn_sched_barrier(0);
        __builtin_amdgcn_s_barrier();
        __builtin_amdgcn_sched_barrier(0);
        if (kt < 15) {
            const int ktn = kt + 1;
            #pragma unroll
            for (int i = 0; i < 2; ++i) {
                const int c = (i * 4 + w) * 64 + l;
                const int row = c >> 3, sch = (c & 7) ^ (row & 7);
                G2L(kb + (long)(b * 1024 + ktn * 64 + row) * 2304 + sch * 8, &Ks[cur ^ 1][(i * 4 + w) * 512]);
                G2L(vb + (long)row * 1024 + ktn * 64 + sch * 8, &Vts[cur ^ 1][(i * 4 + w) * 512]);
            }
        }
        __builtin_amdgcn_sched_barrier(0);
        // S = Q @ K^T for both q-groups; K fragment read once, used twice
        f32x4 s[2][4];
        #pragma unroll
        for (int qg = 0; qg < 2; ++qg)
            #pragma unroll
            for (int kc = 0; kc < 4; ++kc) s[qg][kc] = z;
        #pragma unroll
        for (int kk = 0; kk < 2; ++kk) {
            #pragma unroll
            for (int kc = 0; kc < 4; ++kc) {
                const int row = kc * 16 + lr;
                bf16x8 bk = *reinterpret_cast<const bf16x8*>(&Ks[cur][row * 64 + (((kk * 4 + lg) ^ (lr & 7)) << 3)]);
                s[0][kc] = mfma16(aq[0][kk], bk, s[0][kc]);
                s[1][kc] = mfma16(aq[1][kk], bk, s[1][kc]);
            }
        }
        // softmax-lite + permuted-P pack, per q-group
        #pragma unroll
        for (int qg = 0; qg < 2; ++qg) {
            #pragma unroll
            for (int r = 0; r < 4; ++r) {
                const float p0 = fast_exp2(s[qg][0][r] * sc2);
                const float p1 = fast_exp2(s[qg][1][r] * sc2);
                const float p2 = fast_exp2(s[qg][2][r] * sc2);
                const float p3 = fast_exp2(s[qg][3][r] * sc2);
                lacc[qg][r] += (p0 + p1) + (p2 + p3);
                const unsigned w0 = pack_bf16(p0, p1);
                const unsigned w1 = pack_bf16(p2, p3);
                const int q = lg * 4 + r;
                const int csw = (lr >> 1) ^ (q & 7);
                *reinterpret_cast<uint2*>(&Ps[w * 2048 + qg * 1024 + q * 64 + csw * 8 + (lr & 1) * 4]) =
                    make_uint2(w0, w1);
            }
        }
        // O += P @ V; V fragment read once, used for both q-groups
        #pragma unroll
        for (int kk = 0; kk < 2; ++kk) {
            const int swzk = ((kk * 4 + lg) ^ (lr & 7)) << 3;
            bf16x8 pa0 = *reinterpret_cast<const bf16x8*>(&Ps[w * 2048 + lr * 64 + swzk]);
            bf16x8 pa1 = *reinterpret_cast<const bf16x8*>(&Ps[w * 2048 + 1024 + lr * 64 + swzk]);
            #pragma unroll
            for (int n = 0; n < 4; ++n) {
                const int row = n * 16 + lr;
                bf16x8 vbf = *reinterpret_cast<const bf16x8*>(&Vts[cur][row * 64 + swzk]);
                o[0][n] = mfma16(pa0, vbf, o[0][n]);
                o[1][n] = mfma16(pa1, vbf, o[1][n]);
            }
        }
    }
    #pragma unroll
    for (int qg = 0; qg < 2; ++qg) {
        #pragma unroll
        for (int r = 0; r < 4; ++r) {
            float rs = lacc[qg][r];
            #pragma unroll
            for (int off = 1; off < 16; off <<= 1) rs += __shfl_xor(rs, off, 64);
            lacc[qg][r] = rs;
        }
        const int qrow = qt * 128 + qg * 64 + w * 16 + lg * 4;
        #pragma unroll
        for (int n = 0; n < 4; ++n) {
            #pragma unroll
            for (int r = 0; r < 4; ++r) {
                const float v = o[qg][n][r] / lacc[qg][r];
                outp[(long)(b * 1024 + qrow + r) * 768 + h * 64 + n * 16 + lr] = f32_to_bf16(v);
            }
        }
    }
}

extern "C" void kernel_launch(void* const* d_in, const int* in_sizes, int n_in,
                              void* d_out, int out_size, void* d_ws, size_t ws_size,
                              hipStream_t stream) {
    (void)in_sizes; (void)n_in; (void)out_size; (void)ws_size;
    const float* x    = (const float*)d_in[0];
    const float* Wqkv = (const float*)d_in[1];
    const float* bqkv = (const float*)d_in[2];
    const float* Wout = (const float*)d_in[3];
    const float* bout = (const float*)d_in[4];

    u16* xb   = (u16*)d_ws;          // 8192*768
    u16* Wqb  = xb  + 6291456;       // 2304*768
    u16* Wob  = Wqb + 1769472;       // 768*768
    u16* qkv  = Wob + 589824;        // 8192*2304
    u16* vtb  = qkv + 18874368;      // 96*64*1024
    u16* attn = vtb + 6291456;       // 8192*768

    cvt3_k<<<8448, 256, 0, stream>>>(x, Wqkv, Wout, xb);

    gemm_bt_k<0><<<1152, 256, 0, stream>>>(xb, Wqb, bqkv, qkv, 8192, 2304, 768, 18);
    transpose_v_k<<<dim3(16, 96), 256, 0, stream>>>(qkv, vtb);
    attn_k<<<768, 256, 0, stream>>>(qkv, vtb, attn);
    gemm_bt_k<1><<<384, 256, 0, stream>>>(attn, Wob, bout, d_out, 8192, 768, 768, 6);
}

// Round 10
// 102.730 us; speedup vs baseline: 1.3591x; 1.1141x over previous
//
#include <hip/hip_runtime.h>
#include <stdint.h>

typedef __bf16 bf16x8 __attribute__((ext_vector_type(8)));
typedef float  f32x4  __attribute__((ext_vector_type(4)));
typedef unsigned short u16;

#define AS1 __attribute__((address_space(1)))
#define AS3 __attribute__((address_space(3)))
#define G2L(gp, lp) __builtin_amdgcn_global_load_lds( \
    (const AS1 unsigned int*)(uintptr_t)(gp), \
    (AS3 unsigned int*)(uintptr_t)(lp), 16, 0, 0)

static __device__ __forceinline__ u16 f32_to_bf16(float f) {
    unsigned u = __float_as_uint(f);
    u += 0x7fffu + ((u >> 16) & 1u);
    return (u16)(u >> 16);
}

// bf16 pair pack: lo -> bits[15:0], hi -> bits[31:16]
static __device__ __forceinline__ unsigned pack_bf16(float lo, float hi) {
    return (unsigned)f32_to_bf16(lo) | ((unsigned)f32_to_bf16(hi) << 16);
}

static __device__ __forceinline__ float fast_exp2(float x) {
    return __builtin_amdgcn_exp2f(x);
}

static __device__ __forceinline__ f32x4 mfma16(bf16x8 a, bf16x8 b, f32x4 c) {
    return __builtin_amdgcn_mfma_f32_16x16x32_bf16(a, b, c, 0, 0, 0);
}

// ---------------- fused fp32 -> bf16 convert for x, W_qkv, W_out ----------------
__global__ void cvt3_k(const float* __restrict__ a, const float* __restrict__ b,
                       const float* __restrict__ c, u16* __restrict__ out) {
    const int i = blockIdx.x * blockDim.x + threadIdx.x;   // vec4 index
    const float* src; int off;
    if (i < 1572864)      { src = a; off = 0; }
    else if (i < 2015232) { src = b; off = 1572864; }
    else                  { src = c; off = 2015232; }
    const float4 v = reinterpret_cast<const float4*>(src)[i - off];
    reinterpret_cast<uint2*>(out)[i] = make_uint2(pack_bf16(v.x, v.y), pack_bf16(v.z, v.w));
}

// ---------------- bf16 GEMM: C[M,N] = A[M,K] @ B[N,K]^T + bias ----------------
// 128x128 tile, BK=64, 2-phase prefetch, dbuf LDS, XCD swizzle.
// Columns gc < qcols get scaled by qsc (pre-folds softmax scale into Q).
template<int OUTF32>
__global__ __launch_bounds__(256, 2) void gemm_bt_k(const u16* __restrict__ A, const u16* __restrict__ B,
                                                    const float* __restrict__ bias, void* __restrict__ Cp,
                                                    int M, int N, int K, int nbx, int qcols, float qsc) {
    __shared__ __align__(16) u16 As[2][128 * 64];
    __shared__ __align__(16) u16 Bs[2][128 * 64];
    const int id = blockIdx.x;
    const int cpx = gridDim.x >> 3;
    const int swz = (id & 7) * cpx + (id >> 3);
    const int bx = swz % nbx, by = swz / nbx;
    const int t = threadIdx.x, w = t >> 6, l = t & 63, lr = l & 15, lg = l >> 4;
    const int wr = w >> 1, wc = w & 1;
    const long rowBase = (long)by * 128;
    const long colBase = (long)bx * 128;

    const f32x4 z = {0.f, 0.f, 0.f, 0.f};
    f32x4 acc[4][4];
    #pragma unroll
    for (int m = 0; m < 4; ++m)
        #pragma unroll
        for (int n = 0; n < 4; ++n) acc[m][n] = z;

    const int kSteps = K >> 6;
    #pragma unroll
    for (int i = 0; i < 4; ++i) {
        const int c = i * 256 + t, row = c >> 3, ch = c & 7;
        const int sch = ch ^ (row & 7);
        G2L(A + (rowBase + row) * K + sch * 8, &As[0][(i * 256 + w * 64) * 8]);
        G2L(B + (colBase + row) * K + sch * 8, &Bs[0][(i * 256 + w * 64) * 8]);
    }
    for (int kt = 0; kt < kSteps; ++kt) {
        const int cur = kt & 1;
        asm volatile("s_waitcnt vmcnt(0)" ::: "memory");
        __builtin_amdgcn_sched_barrier(0);
        __builtin_amdgcn_s_barrier();
        __builtin_amdgcn_sched_barrier(0);
        if (kt + 1 < kSteps) {
            const int k0 = (kt + 1) << 6;
            #pragma unroll
            for (int i = 0; i < 4; ++i) {
                const int c = i * 256 + t, row = c >> 3, ch = c & 7;
                const int sch = ch ^ (row & 7);
                G2L(A + (rowBase + row) * K + k0 + sch * 8, &As[cur ^ 1][(i * 256 + w * 64) * 8]);
                G2L(B + (colBase + row) * K + k0 + sch * 8, &Bs[cur ^ 1][(i * 256 + w * 64) * 8]);
            }
        }
        __builtin_amdgcn_sched_barrier(0);
        #pragma unroll
        for (int kk = 0; kk < 2; ++kk) {
            bf16x8 af[4], bfr[4];
            #pragma unroll
            for (int m = 0; m < 4; ++m) {
                const int row = wr * 64 + m * 16 + lr;
                af[m] = *reinterpret_cast<const bf16x8*>(&As[cur][row * 64 + (((kk * 4 + lg) ^ (lr & 7)) << 3)]);
            }
            #pragma unroll
            for (int n = 0; n < 4; ++n) {
                const int row = wc * 64 + n * 16 + lr;
                bfr[n] = *reinterpret_cast<const bf16x8*>(&Bs[cur][row * 64 + (((kk * 4 + lg) ^ (lr & 7)) << 3)]);
            }
            #pragma unroll
            for (int m = 0; m < 4; ++m)
                #pragma unroll
                for (int n = 0; n < 4; ++n) acc[m][n] = mfma16(af[m], bfr[n], acc[m][n]);
        }
    }
    #pragma unroll
    for (int n = 0; n < 4; ++n) {
        const long gc = colBase + wc * 64 + n * 16 + lr;
        const float bv = bias[gc];
        const float csc = (gc < qcols) ? qsc : 1.0f;
        #pragma unroll
        for (int m = 0; m < 4; ++m) {
            const long gr = rowBase + wr * 64 + m * 16 + lg * 4;
            #pragma unroll
            for (int r = 0; r < 4; ++r) {
                const float v = (acc[m][n][r] + bv) * csc;
                if (OUTF32) reinterpret_cast<float*>(Cp)[(gr + r) * N + gc] = v;
                else        reinterpret_cast<u16*>(Cp)[(gr + r) * N + gc] = f32_to_bf16(v);
            }
        }
    }
}

// ---------------- V transpose with PV k-permutation pi' (R7-proven) ----------------
// vt[bh][d][pos p] = V[key = (p>>5)*32 + ((p>>2)&1)*16 + ((p>>3)&3)*4 + (p&3)][d]
__global__ __launch_bounds__(256) void transpose_v_k(const u16* __restrict__ qkv, u16* __restrict__ vt) {
    const int bh = blockIdx.y, b = bh / 12, h = bh % 12;
    const int nt = blockIdx.x;
    __shared__ __align__(16) u16 Ts[64][72];   // [key][d]
    const int t = threadIdx.x;
    const int rr = t >> 2;
    #pragma unroll
    for (int i = 0; i < 2; ++i) {
        const int ch = (t & 3) + i * 4;
        const u16* src = qkv + (long)(b * 1024 + nt * 64 + rr) * 2304 + 1536 + h * 64 + ch * 8;
        *reinterpret_cast<uint4*>(&Ts[rr][ch * 8]) = *reinterpret_cast<const uint4*>(src);
    }
    __syncthreads();
    #pragma unroll
    for (int i = 0; i < 2; ++i) {
        const int ch = (t & 3) + i * 4;   // pos p = ch*8+j
        u16 vals[8];
        #pragma unroll
        for (int j = 0; j < 8; ++j)
            vals[j] = Ts[(ch >> 2) * 32 + (j >> 2) * 16 + (ch & 3) * 4 + (j & 3)][rr];
        u16* dst = vt + (long)(bh * 64 + rr) * 1024 + nt * 64 + ch * 8;
        *reinterpret_cast<uint4*>(dst) = *reinterpret_cast<const uint4*>(vals);
    }
}

// ---------------- flash attention v7: swapped-QK, in-register P, QBLK=128 ----------------
// s = mfma(K, Q): lane holds P[q=qf*16+lr] -> P packs feed PV A-operand directly
// (no P LDS round-trip). Denominator via ones-MFMA (dacc matches o's row layout).
// K/V LDS-staged with G2L dbuf; Q pre-scaled by 768^-0.5*log2e in gemm1 epilogue.
__global__ __launch_bounds__(256, 3) void attn_k(const u16* __restrict__ qkv, const u16* __restrict__ vt,
                                                 u16* __restrict__ outp) {
    const int id = blockIdx.x;
    const int bh = id % 96, qt = id / 96;   // qt in 0..7; same-bh -> same XCD
    const int b = bh / 12, h = bh % 12;
    const int t = threadIdx.x, w = t >> 6, l = t & 63, lr = l & 15, lg = l >> 4;
    __shared__ __align__(16) u16 Ks[2][64 * 64];
    __shared__ __align__(16) u16 Vts[2][64 * 64];   // [d][perm key]

    const u16* kb = qkv + 768 + h * 64;
    const u16* vb = vt + (long)bh * 64 * 1024;

    // stage K/V tile 0
    #pragma unroll
    for (int i = 0; i < 2; ++i) {
        const int c = (i * 4 + w) * 64 + l;
        const int row = c >> 3, sch = (c & 7) ^ (row & 7);
        G2L(kb + (long)(b * 1024 + row) * 2304 + sch * 8, &Ks[0][(i * 4 + w) * 512]);
        G2L(vb + (long)row * 1024 + sch * 8, &Vts[0][(i * 4 + w) * 512]);
    }
    // Q (pre-scaled in gemm1) straight into regs: B-operand rows q = w*32+qf*16+lr
    const u16* qb = qkv + (long)(b * 1024 + qt * 128 + w * 32) * 2304 + h * 64;
    bf16x8 aq[2][2];
    #pragma unroll
    for (int qf = 0; qf < 2; ++qf)
        #pragma unroll
        for (int kk = 0; kk < 2; ++kk)
            aq[qf][kk] = *reinterpret_cast<const bf16x8*>(qb + (long)(qf * 16 + lr) * 2304 + (kk * 4 + lg) * 8);

    const f32x4 z = {0.f, 0.f, 0.f, 0.f};
    f32x4 o[2][4];      // [qf][n]: O[q=qf*16+lg*4+r][d=n*16+lr]
    f32x4 dacc[2];      // [qf]: denom[q=qf*16+lg*4+r] (all cols identical)
    #pragma unroll
    for (int qf = 0; qf < 2; ++qf) {
        #pragma unroll
        for (int n = 0; n < 4; ++n) o[qf][n] = z;
        dacc[qf] = z;
    }
    // ones vector for denominator MFMA
    const unsigned one2 = 0x3F803F80u;
    uint4 onesu = make_uint4(one2, one2, one2, one2);
    const bf16x8 ones = *reinterpret_cast<const bf16x8*>(&onesu);

    #pragma unroll 2
    for (int kt = 0; kt < 16; ++kt) {
        const int cur = kt & 1;
        asm volatile("s_waitcnt vmcnt(0)" ::: "memory");
        __builtin_amdgcn_sched_barrier(0);
        __builtin_amdgcn_s_barrier();
        __builtin_amdgcn_sched_barrier(0);
        if (kt < 15) {
            const int ktn = kt + 1;
            #pragma unroll
            for (int i = 0; i < 2; ++i) {
                const int c = (i * 4 + w) * 64 + l;
                const int row = c >> 3, sch = (c & 7) ^ (row & 7);
                G2L(kb + (long)(b * 1024 + ktn * 64 + row) * 2304 + sch * 8, &Ks[cur ^ 1][(i * 4 + w) * 512]);
                G2L(vb + (long)row * 1024 + ktn * 64 + sch * 8, &Vts[cur ^ 1][(i * 4 + w) * 512]);
            }
        }
        __builtin_amdgcn_sched_barrier(0);
        // S^T = K @ Q^T: s[kc][qf] = S[key=kc*16+lg*4+r][q=qf*16+lr]
        f32x4 s[4][2];
        #pragma unroll
        for (int kc = 0; kc < 4; ++kc)
            #pragma unroll
            for (int qf = 0; qf < 2; ++qf) s[kc][qf] = z;
        #pragma unroll
        for (int kk = 0; kk < 2; ++kk) {
            #pragma unroll
            for (int kc = 0; kc < 4; ++kc) {
                const int row = kc * 16 + lr;
                bf16x8 bk = *reinterpret_cast<const bf16x8*>(&Ks[cur][row * 64 + (((kk * 4 + lg) ^ (lr & 7)) << 3)]);
                s[kc][0] = mfma16(bk, aq[0][kk], s[kc][0]);
                s[kc][1] = mfma16(bk, aq[1][kk], s[kc][1]);
            }
        }
        // softmax-lite in-register: p = exp2(s) (Q pre-scaled), pack to PV A-operand
        // pa[qf][kk] pos j=c*4+r <- pv[2kk+c][r]  (pi' on both sides)
        #pragma unroll
        for (int qf = 0; qf < 2; ++qf) {
            float pv[4][4];
            #pragma unroll
            for (int kc = 0; kc < 4; ++kc)
                #pragma unroll
                for (int r = 0; r < 4; ++r)
                    pv[kc][r] = fast_exp2(s[kc][qf][r]);
            uint4 u0, u1;
            u0.x = pack_bf16(pv[0][0], pv[0][1]); u0.y = pack_bf16(pv[0][2], pv[0][3]);
            u0.z = pack_bf16(pv[1][0], pv[1][1]); u0.w = pack_bf16(pv[1][2], pv[1][3]);
            u1.x = pack_bf16(pv[2][0], pv[2][1]); u1.y = pack_bf16(pv[2][2], pv[2][3]);
            u1.z = pack_bf16(pv[3][0], pv[3][1]); u1.w = pack_bf16(pv[3][2], pv[3][3]);
            bf16x8 pa0 = *reinterpret_cast<bf16x8*>(&u0);
            bf16x8 pa1 = *reinterpret_cast<bf16x8*>(&u1);
            // denominator: ones-MFMA (row layout matches o)
            dacc[qf] = mfma16(pa0, ones, dacc[qf]);
            dacc[qf] = mfma16(pa1, ones, dacc[qf]);
            // O += P @ V
            #pragma unroll
            for (int kk = 0; kk < 2; ++kk) {
                const bf16x8 pa = kk ? pa1 : pa0;
                const int swzk = ((kk * 4 + lg) ^ (lr & 7)) << 3;
                #pragma unroll
                for (int n = 0; n < 4; ++n) {
                    const int row = n * 16 + lr;
                    bf16x8 vbf = *reinterpret_cast<const bf16x8*>(&Vts[cur][row * 64 + swzk]);
                    o[qf][n] = mfma16(pa, vbf, o[qf][n]);
                }
            }
        }
    }
    // epilogue: divide by denom (dacc row layout == o row layout), store
    #pragma unroll
    for (int qf = 0; qf < 2; ++qf) {
        const int qrow = qt * 128 + w * 32 + qf * 16 + lg * 4;
        #pragma unroll
        for (int r = 0; r < 4; ++r) {
            const float inv = 1.0f / dacc[qf][r];
            #pragma unroll
            for (int n = 0; n < 4; ++n) {
                outp[(long)(b * 1024 + qrow + r) * 768 + h * 64 + n * 16 + lr] =
                    f32_to_bf16(o[qf][n][r] * inv);
            }
        }
    }
}

extern "C" void kernel_launch(void* const* d_in, const int* in_sizes, int n_in,
                              void* d_out, int out_size, void* d_ws, size_t ws_size,
                              hipStream_t stream) {
    (void)in_sizes; (void)n_in; (void)out_size; (void)ws_size;
    const float* x    = (const float*)d_in[0];
    const float* Wqkv = (const float*)d_in[1];
    const float* bqkv = (const float*)d_in[2];
    const float* Wout = (const float*)d_in[3];
    const float* bout = (const float*)d_in[4];

    u16* xb   = (u16*)d_ws;          // 8192*768
    u16* Wqb  = xb  + 6291456;       // 2304*768
    u16* Wob  = Wqb + 1769472;       // 768*768
    u16* qkv  = Wob + 589824;        // 8192*2304
    u16* vtb  = qkv + 18874368;      // 96*64*1024
    u16* attn = vtb + 6291456;       // 8192*768

    const float sc2 = 0.052058773f;  // 768^-0.5 * log2(e)

    cvt3_k<<<8448, 256, 0, stream>>>(x, Wqkv, Wout, xb);

    gemm_bt_k<0><<<1152, 256, 0, stream>>>(xb, Wqb, bqkv, qkv, 8192, 2304, 768, 18, 768, sc2);
    transpose_v_k<<<dim3(16, 96), 256, 0, stream>>>(qkv, vtb);
    attn_k<<<768, 256, 0, stream>>>(qkv, vtb, attn);
    gemm_bt_k<1><<<384, 256, 0, stream>>>(attn, Wob, bout, d_out, 8192, 768, 768, 6, 0, 1.0f);
}